// Round 7
// baseline (37.461 us; speedup 1.0000x reference)
//
#include <hip/hip_runtime.h>
#include <hip/hip_bf16.h>

typedef __attribute__((ext_vector_type(8))) short bf16x8;
typedef __attribute__((ext_vector_type(4))) float f32x4;

__device__ __forceinline__ unsigned short f2bf(float f) {
    unsigned u = __builtin_bit_cast(unsigned, f);
    unsigned rnd = 0x7FFFu + ((u >> 16) & 1u);
    return (unsigned short)((u + rnd) >> 16);
}

// ---------------------------------------------------------------------------
// Setup: simulate the circuit on the 256 basis vectors -> U (256x256),
// packed as bf16 B-fragments for mfma_f32_16x16x32_bf16 (proven layout):
//   element (n,k): u=n>>4, t=k>>5, lane=((k>>3)&3)*16+(n&15), j=k&7
//   Bp[((u*8+t)*64 + lane)*8 + j]
// ---------------------------------------------------------------------------
__global__ __launch_bounds__(256) void qnn_setup(const float* __restrict__ wts,
                                                 unsigned short* __restrict__ Bp) {
    __shared__ float cs[56], sn[56];
    int tid = threadIdx.x;
    if (tid < 56) {
        float th = 0.5f * wts[tid];
        cs[tid] = cosf(th);
        sn[tid] = sinf(th);
    }
    __syncthreads();

    int l = tid & 63;
    int k = blockIdx.x * 4 + (tid >> 6);   // column 0..255
    int a0 = l << 2;

    float v0 = (float)(a0 + 0 == k);
    float v1 = (float)(a0 + 1 == k);
    float v2 = (float)(a0 + 2 == k);
    float v3 = (float)(a0 + 3 == k);

#pragma unroll
    for (int L = 0; L < 7; ++L) {
#pragma unroll
        for (int q = 0; q <= 5; ++q) {     // RY wires 0..5 (lane bits)
            int m = 5 - q;
            float c = cs[L * 8 + q], s = sn[L * 8 + q];
            float ss = ((l >> m) & 1) ? s : -s;
            float p0 = __shfl_xor(v0, 1 << m);
            float p1 = __shfl_xor(v1, 1 << m);
            float p2 = __shfl_xor(v2, 1 << m);
            float p3 = __shfl_xor(v3, 1 << m);
            v0 = fmaf(ss, p0, c * v0);
            v1 = fmaf(ss, p1, c * v1);
            v2 = fmaf(ss, p2, c * v2);
            v3 = fmaf(ss, p3, c * v3);
        }
        {   // RY wire 6 (reg bit 1)
            float c = cs[L * 8 + 6], s = sn[L * 8 + 6];
            float n0 = fmaf(-s, v2, c * v0), n2 = fmaf(s, v0, c * v2);
            float n1 = fmaf(-s, v3, c * v1), n3 = fmaf(s, v1, c * v3);
            v0 = n0; v1 = n1; v2 = n2; v3 = n3;
        }
        {   // RY wire 7 (reg bit 0)
            float c = cs[L * 8 + 7], s = sn[L * 8 + 7];
            float n0 = fmaf(-s, v1, c * v0), n1 = fmaf(s, v0, c * v1);
            float n2 = fmaf(-s, v3, c * v2), n3 = fmaf(s, v2, c * v3);
            v0 = n0; v1 = n1; v2 = n2; v3 = n3;
        }
        {   // CNOTs q=0..4 (both bits in lane index): composed lane permute
            int src = l;
#pragma unroll
            for (int q = 4; q >= 0; --q)
                src = src ^ (((src >> (5 - q)) & 1) << (4 - q));
            v0 = __shfl(v0, src);
            v1 = __shfl(v1, src);
            v2 = __shfl(v2, src);
            v3 = __shfl(v3, src);
        }
        {   // CNOT q=5: ctl = lane bit0, tgt = reg bit1
            bool cc = (l & 1);
            float n0 = cc ? v2 : v0, n2 = cc ? v0 : v2;
            float n1 = cc ? v3 : v1, n3 = cc ? v1 : v3;
            v0 = n0; v1 = n1; v2 = n2; v3 = n3;
        }
        {   // CNOT q=6: swap v2,v3
            float t = v2; v2 = v3; v3 = t;
        }
    }

    int t = k >> 5, j = k & 7, lk = (k >> 3) & 3;
#pragma unroll
    for (int r = 0; r < 4; ++r) {
        int n = a0 + r;
        int u = n >> 4;
        int ls = lk * 16 + (n & 15);
        float val = (r == 0) ? v0 : (r == 1) ? v1 : (r == 2) ? v2 : v3;
        Bp[(((u * 8 + t) * 64) + ls) * 8 + j] = f2bf(val);
    }
}

// ---------------------------------------------------------------------------
// Main (R7): 2048 independent 1-wave blocks (64 thr), 8 blocks/CU, NO LDS,
// NO barriers. B-fragments streamed straight from L2 (U = 128 KB, resident
// per-XCD) with explicit register double-buffering (ba/bb, next u-pair's 16
// loads issued before current pair's 32 MFMAs). A: 32 float4 in one burst
// (VGPR cap 256 keeps them all in flight). Latency hidden by ILP + 8
// desynchronized blocks/CU.
// ---------------------------------------------------------------------------
__global__ __launch_bounds__(64, 2) void qnn_main(
    const float* __restrict__ x, const unsigned short* __restrict__ Bp,
    const float* __restrict__ W1, const float* __restrict__ b1,
    const float* __restrict__ W2, const float* __restrict__ b2,
    float* __restrict__ out) {
    int l = threadIdx.x;                                   // 0..63
    size_t base = (size_t)blockIdx.x * 32 * 256;           // 32 samples/block

    // ---- A loads: one burst of 32 dwordx4 (deepest latency, issued first) ----
    const float* xr0 = x + base + (size_t)(l & 15) * 256 + (l >> 4) * 8;
    const float* xr1 = xr0 + 16 * 256;
    float4 fa0[16], fa1[16];
#pragma unroll
    for (int t = 0; t < 8; ++t) {
        fa0[2 * t]     = *(const float4*)(xr0 + t * 32);
        fa0[2 * t + 1] = *(const float4*)(xr0 + t * 32 + 4);
    }
#pragma unroll
    for (int t = 0; t < 8; ++t) {
        fa1[2 * t]     = *(const float4*)(xr1 + t * 32);
        fa1[2 * t + 1] = *(const float4*)(xr1 + t * 32 + 4);
    }

    // ---- B u-pair 0 into register buffer A (L2-hot) ----
    const unsigned short* bbase = Bp + l * 8;
    bf16x8 ba[16], bb[16];
#pragma unroll
    for (int t = 0; t < 16; ++t)
        ba[t] = *(const bf16x8*)(bbase + t * 512);

    // ---- convert + norms (depends only on A loads) ----
    bf16x8 af0[8], af1[8];
    float ss0 = 0.f, ss1 = 0.f;
#pragma unroll
    for (int t = 0; t < 8; ++t) {
        float4 f0 = fa0[2 * t], f1 = fa0[2 * t + 1];
        ss0 = fmaf(f0.x, f0.x, fmaf(f0.y, f0.y, fmaf(f0.z, f0.z, fmaf(f0.w, f0.w, ss0))));
        ss0 = fmaf(f1.x, f1.x, fmaf(f1.y, f1.y, fmaf(f1.z, f1.z, fmaf(f1.w, f1.w, ss0))));
        bf16x8 a;
        a[0] = (short)f2bf(f0.x); a[1] = (short)f2bf(f0.y);
        a[2] = (short)f2bf(f0.z); a[3] = (short)f2bf(f0.w);
        a[4] = (short)f2bf(f1.x); a[5] = (short)f2bf(f1.y);
        a[6] = (short)f2bf(f1.z); a[7] = (short)f2bf(f1.w);
        af0[t] = a;
    }
#pragma unroll
    for (int t = 0; t < 8; ++t) {
        float4 f0 = fa1[2 * t], f1 = fa1[2 * t + 1];
        ss1 = fmaf(f0.x, f0.x, fmaf(f0.y, f0.y, fmaf(f0.z, f0.z, fmaf(f0.w, f0.w, ss1))));
        ss1 = fmaf(f1.x, f1.x, fmaf(f1.y, f1.y, fmaf(f1.z, f1.z, fmaf(f1.w, f1.w, ss1))));
        bf16x8 a;
        a[0] = (short)f2bf(f0.x); a[1] = (short)f2bf(f0.y);
        a[2] = (short)f2bf(f0.z); a[3] = (short)f2bf(f0.w);
        a[4] = (short)f2bf(f1.x); a[5] = (short)f2bf(f1.y);
        a[6] = (short)f2bf(f1.z); a[7] = (short)f2bf(f1.w);
        af1[t] = a;
    }
    ss0 += __shfl_xor(ss0, 16); ss0 += __shfl_xor(ss0, 32);
    ss1 += __shfl_xor(ss1, 16); ss1 += __shfl_xor(ss1, 32);

    // ---- main loop: 8 u-pairs, register-double-buffered B stream ----
    float q0[4] = {0.f, 0.f, 0.f, 0.f};
    float q1[4] = {0.f, 0.f, 0.f, 0.f};
#pragma unroll
    for (int up = 0; up < 8; ++up) {
        const bf16x8* cur = (up & 1) ? bb : ba;
        bf16x8* nxt = (up & 1) ? ba : bb;
        if (up < 7) {
            const unsigned short* srcn = bbase + (size_t)(up + 1) * 16 * 512;
#pragma unroll
            for (int t = 0; t < 16; ++t)
                nxt[t] = *(const bf16x8*)(srcn + t * 512);
        }
        f32x4 a00 = {0.f, 0.f, 0.f, 0.f}, a01 = {0.f, 0.f, 0.f, 0.f};
        f32x4 a10 = {0.f, 0.f, 0.f, 0.f}, a11 = {0.f, 0.f, 0.f, 0.f};
#pragma unroll
        for (int t = 0; t < 8; ++t) {
            a00 = __builtin_amdgcn_mfma_f32_16x16x32_bf16(af0[t], cur[t],     a00, 0, 0, 0);
            a10 = __builtin_amdgcn_mfma_f32_16x16x32_bf16(af1[t], cur[t],     a10, 0, 0, 0);
            a01 = __builtin_amdgcn_mfma_f32_16x16x32_bf16(af0[t], cur[8 + t], a01, 0, 0, 0);
            a11 = __builtin_amdgcn_mfma_f32_16x16x32_bf16(af1[t], cur[8 + t], a11, 0, 0, 0);
        }
        float sgn = (up < 4) ? 1.f : -1.f;   // u-pair < 4 <=> n < 128
#pragma unroll
        for (int j = 0; j < 4; ++j) {
            q0[j] = fmaf(sgn * a00[j], a00[j], q0[j]);
            q0[j] = fmaf(sgn * a01[j], a01[j], q0[j]);
            q1[j] = fmaf(sgn * a10[j], a10[j], q1[j]);
            q1[j] = fmaf(sgn * a11[j], a11[j], q1[j]);
        }
    }

#pragma unroll
    for (int d = 1; d < 16; d <<= 1) {
#pragma unroll
        for (int j = 0; j < 4; ++j) {
            q0[j] += __shfl_xor(q0[j], d);
            q1[j] += __shfl_xor(q1[j], d);
        }
    }

    // norm for the rows this lane writes (C/D: row=(l>>4)*4+j, col=l&15)
    float nrm0 = __shfl(ss0, ((l >> 4) << 2) | (l & 3));
    float nrm1 = __shfl(ss1, ((l >> 4) << 2) | (l & 3));

    if ((l & 15) < 4) {
        int j = l & 3;
        int r0 = (l >> 4) * 4 + j;
        float qv0 = (j == 0) ? q0[0] : (j == 1) ? q0[1] : (j == 2) ? q0[2] : q0[3];
        float qv1 = (j == 0) ? q1[0] : (j == 1) ? q1[1] : (j == 2) ? q1[2] : q1[3];
        float z0 = qv0 / nrm0;
        float z1 = qv1 / nrm1;
        float o0 = b2[0], o1 = b2[0];
#pragma unroll
        for (int jj = 0; jj < 16; ++jj) {
            float w1v = W1[jj], b1v = b1[jj], w2v = W2[jj];
            float h0 = fmaf(z0, w1v, b1v); h0 = h0 > 0.f ? h0 : 0.f;
            float h1 = fmaf(z1, w1v, b1v); h1 = h1 > 0.f ? h1 : 0.f;
            o0 = fmaf(w2v, h0, o0);
            o1 = fmaf(w2v, h1, o1);
        }
        size_t ob = (size_t)blockIdx.x * 32;
        out[ob + r0]      = 1.f / (1.f + expf(-o0));
        out[ob + r0 + 16] = 1.f / (1.f + expf(-o1));
    }
}

extern "C" void kernel_launch(void* const* d_in, const int* in_sizes, int n_in,
                              void* d_out, int out_size, void* d_ws, size_t ws_size,
                              hipStream_t stream) {
    const float* x   = (const float*)d_in[0];
    const float* wts = (const float*)d_in[1];
    const float* W1  = (const float*)d_in[2];
    const float* b1  = (const float*)d_in[3];
    const float* W2  = (const float*)d_in[4];
    const float* b2  = (const float*)d_in[5];
    float* out = (float*)d_out;
    unsigned short* Bp = (unsigned short*)d_ws;   // 65536 bf16 = 128 KB

    int B = in_sizes[0] >> 8;        // 65536 samples
    qnn_setup<<<64, 256, 0, stream>>>(wts, Bp);
    qnn_main<<<B / 32, 64, 0, stream>>>(x, Bp, W1, b1, W2, b2, out);
}

// Round 8
// 27.880 us; speedup vs baseline: 1.3437x; 1.3437x over previous
//
#include <hip/hip_runtime.h>
#include <hip/hip_bf16.h>

typedef __attribute__((ext_vector_type(8))) short bf16x8;
typedef __attribute__((ext_vector_type(4))) float f32x4;

__device__ __forceinline__ unsigned short f2bf(float f) {
    unsigned u = __builtin_bit_cast(unsigned, f);
    unsigned rnd = 0x7FFFu + ((u >> 16) & 1u);
    return (unsigned short)((u + rnd) >> 16);
}

// ---------------------------------------------------------------------------
// Setup: simulate the circuit on the 256 basis vectors -> U (256x256),
// packed as bf16 fragments (layout identical for A- and B-operand use):
//   element (n,k): u=n>>4, t=k>>5, lane=((k>>3)&3)*16+(n&15), j=k&7
//   Bp[((u*8+t)*64 + lane)*8 + j]
// ---------------------------------------------------------------------------
__global__ __launch_bounds__(256) void qnn_setup(const float* __restrict__ wts,
                                                 unsigned short* __restrict__ Bp) {
    __shared__ float cs[56], sn[56];
    int tid = threadIdx.x;
    if (tid < 56) {
        float th = 0.5f * wts[tid];
        cs[tid] = cosf(th);
        sn[tid] = sinf(th);
    }
    __syncthreads();

    int l = tid & 63;
    int k = blockIdx.x * 4 + (tid >> 6);   // column 0..255
    int a0 = l << 2;

    float v0 = (float)(a0 + 0 == k);
    float v1 = (float)(a0 + 1 == k);
    float v2 = (float)(a0 + 2 == k);
    float v3 = (float)(a0 + 3 == k);

#pragma unroll
    for (int L = 0; L < 7; ++L) {
#pragma unroll
        for (int q = 0; q <= 5; ++q) {     // RY wires 0..5 (lane bits)
            int m = 5 - q;
            float c = cs[L * 8 + q], s = sn[L * 8 + q];
            float ss = ((l >> m) & 1) ? s : -s;
            float p0 = __shfl_xor(v0, 1 << m);
            float p1 = __shfl_xor(v1, 1 << m);
            float p2 = __shfl_xor(v2, 1 << m);
            float p3 = __shfl_xor(v3, 1 << m);
            v0 = fmaf(ss, p0, c * v0);
            v1 = fmaf(ss, p1, c * v1);
            v2 = fmaf(ss, p2, c * v2);
            v3 = fmaf(ss, p3, c * v3);
        }
        {   // RY wire 6 (reg bit 1)
            float c = cs[L * 8 + 6], s = sn[L * 8 + 6];
            float n0 = fmaf(-s, v2, c * v0), n2 = fmaf(s, v0, c * v2);
            float n1 = fmaf(-s, v3, c * v1), n3 = fmaf(s, v1, c * v3);
            v0 = n0; v1 = n1; v2 = n2; v3 = n3;
        }
        {   // RY wire 7 (reg bit 0)
            float c = cs[L * 8 + 7], s = sn[L * 8 + 7];
            float n0 = fmaf(-s, v1, c * v0), n1 = fmaf(s, v0, c * v1);
            float n2 = fmaf(-s, v3, c * v2), n3 = fmaf(s, v2, c * v3);
            v0 = n0; v1 = n1; v2 = n2; v3 = n3;
        }
        {   // CNOTs q=0..4 (both bits in lane index): composed lane permute
            int src = l;
#pragma unroll
            for (int q = 4; q >= 0; --q)
                src = src ^ (((src >> (5 - q)) & 1) << (4 - q));
            v0 = __shfl(v0, src);
            v1 = __shfl(v1, src);
            v2 = __shfl(v2, src);
            v3 = __shfl(v3, src);
        }
        {   // CNOT q=5: ctl = lane bit0, tgt = reg bit1
            bool cc = (l & 1);
            float n0 = cc ? v2 : v0, n2 = cc ? v0 : v2;
            float n1 = cc ? v3 : v1, n3 = cc ? v1 : v3;
            v0 = n0; v1 = n1; v2 = n2; v3 = n3;
        }
        {   // CNOT q=6: swap v2,v3
            float t = v2; v2 = v3; v3 = t;
        }
    }

    int t = k >> 5, j = k & 7, lk = (k >> 3) & 3;
#pragma unroll
    for (int r = 0; r < 4; ++r) {
        int n = a0 + r;
        int u = n >> 4;
        int ls = lk * 16 + (n & 15);
        float val = (r == 0) ? v0 : (r == 1) ? v1 : (r == 2) ? v2 : v3;
        Bp[(((u * 8 + t) * 64) + ls) * 8 + j] = f2bf(val);
    }
}

// ---------------------------------------------------------------------------
// Main (R8): role-inverted GEMM. 1024 blocks x 512 thr (8 waves), 64
// samples/block, 2 resident blocks/CU + queue. Each wave holds TWO u-blocks
// of U register-resident (64 VGPR, loaded once from L2) and computes
// D = U_tile * X^T for all 8 sample-tiles from LDS. U traffic per block:
// 128 KB total (vs 1 MB in R7). Signed partials combined via 2 KB LDS.
// ---------------------------------------------------------------------------
__global__ __launch_bounds__(512, 4) void qnn_main(
    const float* __restrict__ x, const unsigned short* __restrict__ Bp,
    const float* __restrict__ W1, const float* __restrict__ b1,
    const float* __restrict__ W2, const float* __restrict__ b2,
    float* __restrict__ out) {
    __shared__ __align__(16) unsigned short Xs[64][256];   // 32 KB
    __shared__ float Qpart[8][64];                         // 2 KB
    __shared__ float Nrm[64];

    int tid = threadIdx.x;
    int l = tid & 63, w = tid >> 6;                        // wave 0..7
    size_t base = (size_t)blockIdx.x * 64 * 256;           // 64 samples/block

    // ---- persistent U A-frags: u-blocks {2w, 2w+1}, read once from L2 ----
    const unsigned short* u0p = Bp + (size_t)(2 * w) * 4096 + l * 8;
    bf16x8 uf0[8], uf1[8];
#pragma unroll
    for (int t = 0; t < 8; ++t) {
        uf0[t] = *(const bf16x8*)(u0p + t * 512);
        uf1[t] = *(const bf16x8*)(u0p + 4096 + t * 512);
    }

    // ---- stage X: thread = (sample r = tid>>3, eighth qt = tid&7) ----
    // 8 float4 loads (cols qt*32 + 4i), R1-verified swizzle store + norms
    {
        int r = tid >> 3, qt = tid & 7;
        const float4* xr = (const float4*)(x + base + (size_t)r * 256 + qt * 32);
        float4 f[8];
#pragma unroll
        for (int i = 0; i < 8; ++i) f[i] = xr[i];
        float ssum = 0.f;
#pragma unroll
        for (int i = 0; i < 8; ++i) {
            float4 v = f[i];
            ssum = fmaf(v.x, v.x, fmaf(v.y, v.y, fmaf(v.z, v.z, fmaf(v.w, v.w, ssum))));
            ushort4 h;
            h.x = f2bf(v.x); h.y = f2bf(v.y); h.z = f2bf(v.z); h.w = f2bf(v.w);
            int col = qt * 32 + i * 4;
            int swz = (col >> 3) ^ (r & 7);
            *(ushort4*)&Xs[r][swz * 8 + (col & 7)] = h;
        }
        ssum += __shfl_xor(ssum, 1);
        ssum += __shfl_xor(ssum, 2);
        ssum += __shfl_xor(ssum, 4);
        if (qt == 0) Nrm[r] = ssum;
    }
    __syncthreads();

    // ---- main loop: 4 sample-tiles; X-frags from LDS feed 2 u-MFMAs each ----
    int sl = l & 15, kg = l >> 4;
#pragma unroll
    for (int tau = 0; tau < 4; ++tau) {
        int srow = tau * 16 + sl;
        bf16x8 xf[8];
#pragma unroll
        for (int t = 0; t < 8; ++t)
            xf[t] = *(const bf16x8*)&Xs[srow][(((t << 2) + kg) ^ (srow & 7)) * 8];
        f32x4 a0 = {0.f, 0.f, 0.f, 0.f}, a1 = {0.f, 0.f, 0.f, 0.f};
#pragma unroll
        for (int t = 0; t < 8; ++t) {
            a0 = __builtin_amdgcn_mfma_f32_16x16x32_bf16(uf0[t], xf[t], a0, 0, 0, 0);
            a1 = __builtin_amdgcn_mfma_f32_16x16x32_bf16(uf1[t], xf[t], a1, 0, 0, 0);
        }
        // D: col = sample (lane&15), row = n-row m = (lane>>4)*4 + j
        float q = 0.f;
#pragma unroll
        for (int j = 0; j < 4; ++j)
            q = fmaf(a0[j], a0[j], fmaf(a1[j], a1[j], q));
        q += __shfl_xor(q, 16);          // sum over the 4 row-groups
        q += __shfl_xor(q, 32);
        if (l < 16) Qpart[w][tau * 16 + l] = q;
    }
    __syncthreads();

    // ---- final: waves 0: sum signed partials, norm, MLP, sigmoid ----
    if (tid < 64) {
        float p = Qpart[0][tid] + Qpart[1][tid] + Qpart[2][tid] + Qpart[3][tid]
                - Qpart[4][tid] - Qpart[5][tid] - Qpart[6][tid] - Qpart[7][tid];
        float z = p / Nrm[tid];
        float o = b2[0];
#pragma unroll
        for (int jj = 0; jj < 16; ++jj) {
            float h = fmaf(z, W1[jj], b1[jj]);
            h = h > 0.f ? h : 0.f;
            o = fmaf(W2[jj], h, o);
        }
        out[(size_t)blockIdx.x * 64 + tid] = 1.f / (1.f + expf(-o));
    }
}

extern "C" void kernel_launch(void* const* d_in, const int* in_sizes, int n_in,
                              void* d_out, int out_size, void* d_ws, size_t ws_size,
                              hipStream_t stream) {
    const float* x   = (const float*)d_in[0];
    const float* wts = (const float*)d_in[1];
    const float* W1  = (const float*)d_in[2];
    const float* b1  = (const float*)d_in[3];
    const float* W2  = (const float*)d_in[4];
    const float* b2  = (const float*)d_in[5];
    float* out = (float*)d_out;
    unsigned short* Bp = (unsigned short*)d_ws;   // 65536 bf16 = 128 KB

    int B = in_sizes[0] >> 8;        // 65536 samples
    qnn_setup<<<64, 256, 0, stream>>>(wts, Bp);
    qnn_main<<<B / 64, 512, 0, stream>>>(x, Bp, W1, b1, W2, b2, out);
}

// Round 9
// 26.314 us; speedup vs baseline: 1.4236x; 1.0595x over previous
//
#include <hip/hip_runtime.h>
#include <hip/hip_bf16.h>

typedef __attribute__((ext_vector_type(8))) short bf16x8;
typedef __attribute__((ext_vector_type(4))) float f32x4;

__device__ __forceinline__ unsigned short f2bf(float f) {
    unsigned u = __builtin_bit_cast(unsigned, f);
    unsigned rnd = 0x7FFFu + ((u >> 16) & 1u);
    return (unsigned short)((u + rnd) >> 16);
}

// raw barrier: lgkmcnt drain (LDS writes visible) WITHOUT vmcnt drain, so
// register-prefetch global loads stay in flight across the barrier.
__device__ __forceinline__ void wg_barrier() {
    asm volatile("s_waitcnt lgkmcnt(0)" ::: "memory");
    __builtin_amdgcn_sched_barrier(0);
    __builtin_amdgcn_s_barrier();
    __builtin_amdgcn_sched_barrier(0);
}

// ---------------------------------------------------------------------------
// Setup: simulate the circuit on the 256 basis vectors -> U (256x256),
// packed as bf16 fragments (same map for A- or B-operand use; R8-verified):
//   element (n,k): u=n>>4, t=k>>5, lane=((k>>3)&3)*16+(n&15), j=k&7
//   Bp[((u*8+t)*64 + lane)*8 + j]
// ---------------------------------------------------------------------------
__global__ __launch_bounds__(256) void qnn_setup(const float* __restrict__ wts,
                                                 unsigned short* __restrict__ Bp) {
    __shared__ float cs[56], sn[56];
    int tid = threadIdx.x;
    if (tid < 56) {
        float th = 0.5f * wts[tid];
        cs[tid] = cosf(th);
        sn[tid] = sinf(th);
    }
    __syncthreads();

    int l = tid & 63;
    int k = blockIdx.x * 4 + (tid >> 6);   // column 0..255
    int a0 = l << 2;

    float v0 = (float)(a0 + 0 == k);
    float v1 = (float)(a0 + 1 == k);
    float v2 = (float)(a0 + 2 == k);
    float v3 = (float)(a0 + 3 == k);

#pragma unroll
    for (int L = 0; L < 7; ++L) {
#pragma unroll
        for (int q = 0; q <= 5; ++q) {     // RY wires 0..5 (lane bits)
            int m = 5 - q;
            float c = cs[L * 8 + q], s = sn[L * 8 + q];
            float ss = ((l >> m) & 1) ? s : -s;
            float p0 = __shfl_xor(v0, 1 << m);
            float p1 = __shfl_xor(v1, 1 << m);
            float p2 = __shfl_xor(v2, 1 << m);
            float p3 = __shfl_xor(v3, 1 << m);
            v0 = fmaf(ss, p0, c * v0);
            v1 = fmaf(ss, p1, c * v1);
            v2 = fmaf(ss, p2, c * v2);
            v3 = fmaf(ss, p3, c * v3);
        }
        {   // RY wire 6 (reg bit 1)
            float c = cs[L * 8 + 6], s = sn[L * 8 + 6];
            float n0 = fmaf(-s, v2, c * v0), n2 = fmaf(s, v0, c * v2);
            float n1 = fmaf(-s, v3, c * v1), n3 = fmaf(s, v1, c * v3);
            v0 = n0; v1 = n1; v2 = n2; v3 = n3;
        }
        {   // RY wire 7 (reg bit 0)
            float c = cs[L * 8 + 7], s = sn[L * 8 + 7];
            float n0 = fmaf(-s, v1, c * v0), n1 = fmaf(s, v0, c * v1);
            float n2 = fmaf(-s, v3, c * v2), n3 = fmaf(s, v2, c * v3);
            v0 = n0; v1 = n1; v2 = n2; v3 = n3;
        }
        {   // CNOTs q=0..4 (both bits in lane index): composed lane permute
            int src = l;
#pragma unroll
            for (int q = 4; q >= 0; --q)
                src = src ^ (((src >> (5 - q)) & 1) << (4 - q));
            v0 = __shfl(v0, src);
            v1 = __shfl(v1, src);
            v2 = __shfl(v2, src);
            v3 = __shfl(v3, src);
        }
        {   // CNOT q=5: ctl = lane bit0, tgt = reg bit1
            bool cc = (l & 1);
            float n0 = cc ? v2 : v0, n2 = cc ? v0 : v2;
            float n1 = cc ? v3 : v1, n3 = cc ? v1 : v3;
            v0 = n0; v1 = n1; v2 = n2; v3 = n3;
        }
        {   // CNOT q=6: swap v2,v3
            float t = v2; v2 = v3; v3 = t;
        }
    }

    int t = k >> 5, j = k & 7, lk = (k >> 3) & 3;
#pragma unroll
    for (int r = 0; r < 4; ++r) {
        int n = a0 + r;
        int u = n >> 4;
        int ls = lk * 16 + (n & 15);
        float val = (r == 0) ? v0 : (r == 1) ? v1 : (r == 2) ? v2 : v3;
        Bp[(((u * 8 + t) * 64) + ls) * 8 + j] = f2bf(val);
    }
}

__device__ __forceinline__ void issue_loads(const float* xb, float4 (&pf)[4]) {
#pragma unroll
    for (int i = 0; i < 4; ++i) pf[i] = *(const float4*)(xb + i * 4);
}

__device__ __forceinline__ void cvt_store(const float4 (&pf)[4],
                                          unsigned short (*Xp)[256],
                                          float* NrmRow, int sr, int qt) {
    float ssum = 0.f;
#pragma unroll
    for (int i = 0; i < 4; ++i) {
        float4 v = pf[i];
        ssum = fmaf(v.x, v.x, fmaf(v.y, v.y, fmaf(v.z, v.z, fmaf(v.w, v.w, ssum))));
        ushort4 h;
        h.x = f2bf(v.x); h.y = f2bf(v.y); h.z = f2bf(v.z); h.w = f2bf(v.w);
        int chunk = qt * 2 + (i >> 1);          // 16B chunk of cols qt*16+i*4
        int swz = chunk ^ (sr & 7);             // R1-verified XOR swizzle
        *(ushort4*)&Xp[sr][swz * 8 + (i & 1) * 4] = h;
    }
    ssum += __shfl_xor(ssum, 1);
    ssum += __shfl_xor(ssum, 2);
    ssum += __shfl_xor(ssum, 4);
    ssum += __shfl_xor(ssum, 8);
    if (qt == 0) NrmRow[sr] = ssum;             // fp32 norm (pre-bf16)
}

__device__ __forceinline__ void compute_tile(const unsigned short (*Xp)[256],
                                             const bf16x8 (&uf0)[8],
                                             const bf16x8 (&uf1)[8],
                                             float* QpRow, int l, int tbase) {
    int sl = l & 15, kg = l >> 4;
#pragma unroll
    for (int tau = 0; tau < 2; ++tau) {
        int srow = tau * 16 + sl;
        bf16x8 xf[8];
#pragma unroll
        for (int t = 0; t < 8; ++t)
            xf[t] = *(const bf16x8*)&Xp[srow][(((t << 2) + kg) ^ (srow & 7)) * 8];
        f32x4 a0 = {0.f, 0.f, 0.f, 0.f}, a1 = {0.f, 0.f, 0.f, 0.f};
#pragma unroll
        for (int t = 0; t < 8; ++t) {
            a0 = __builtin_amdgcn_mfma_f32_16x16x32_bf16(uf0[t], xf[t], a0, 0, 0, 0);
            a1 = __builtin_amdgcn_mfma_f32_16x16x32_bf16(uf1[t], xf[t], a1, 0, 0, 0);
        }
        // D: col = sample (lane&15); rows reduced via xor 16/32
        float q = 0.f;
#pragma unroll
        for (int j = 0; j < 4; ++j)
            q = fmaf(a0[j], a0[j], fmaf(a1[j], a1[j], q));
        q += __shfl_xor(q, 16);
        q += __shfl_xor(q, 32);
        if (l < 16) QpRow[tbase + tau * 16 + l] = q;
    }
}

// ---------------------------------------------------------------------------
// Main (R9): 256 persistent blocks x 512 thr. U register-resident per wave
// (2 u-blocks, loaded once). X pipelined through double-buffered LDS:
// issue loads(t+2) -> compute(t) -> cvt_store(t+1) -> raw barrier
// (lgkmcnt(0) only; vmcnt NOT drained, prefetch spans barriers).
// ---------------------------------------------------------------------------
__global__ __launch_bounds__(512, 2) void qnn_main(
    const float* __restrict__ x, const unsigned short* __restrict__ Bp,
    const float* __restrict__ W1, const float* __restrict__ b1,
    const float* __restrict__ W2, const float* __restrict__ b2,
    float* __restrict__ out) {
    __shared__ __align__(16) unsigned short Xs[2][32][256];   // 32 KB
    __shared__ float Qpart[8][256];                           // 8 KB
    __shared__ float Nrm[256];                                // 1 KB

    int tid = threadIdx.x;
    int l = tid & 63, w = tid >> 6;                // wave 0..7
    int sr = tid >> 4, qt = tid & 15;              // staging: sample, 16-col slice
    size_t base = (size_t)blockIdx.x * 256 * 256;  // 256 samples/block

    const float* xst = x + base + (size_t)sr * 256 + qt * 16;

    // ---- prologue: issue tile0+tile1 loads, then U frags (all in flight) ----
    float4 pf[2][4];
    issue_loads(xst, pf[0]);
    issue_loads(xst + 8192, pf[1]);

    const unsigned short* u0p = Bp + (size_t)(2 * w) * 4096 + l * 8;
    bf16x8 uf0[8], uf1[8];
#pragma unroll
    for (int t = 0; t < 8; ++t) {
        uf0[t] = *(const bf16x8*)(u0p + t * 512);
        uf1[t] = *(const bf16x8*)(u0p + 4096 + t * 512);
    }

    cvt_store(pf[0], Xs[0], Nrm, sr, qt);          // tile 0 -> Xs[0]
    wg_barrier();

    // ---- 8-tile pipeline ----
#pragma unroll
    for (int t = 0; t < 8; ++t) {
        if (t + 2 < 8) issue_loads(xst + (size_t)(t + 2) * 8192, pf[t & 1]);
        compute_tile(Xs[t & 1], uf0, uf1, Qpart[w], l, t * 32);
        if (t + 1 < 8)
            cvt_store(pf[(t + 1) & 1], Xs[(t + 1) & 1], Nrm + (t + 1) * 32, sr, qt);
        wg_barrier();
    }

    // ---- epilogue: signed combine, norm, MLP, sigmoid ----
    if (tid < 256) {
        float p = Qpart[0][tid] + Qpart[1][tid] + Qpart[2][tid] + Qpart[3][tid]
                - Qpart[4][tid] - Qpart[5][tid] - Qpart[6][tid] - Qpart[7][tid];
        float z = p / Nrm[tid];
        float o = b2[0];
#pragma unroll
        for (int jj = 0; jj < 16; ++jj) {
            float h = fmaf(z, W1[jj], b1[jj]);
            h = h > 0.f ? h : 0.f;
            o = fmaf(W2[jj], h, o);
        }
        out[(size_t)blockIdx.x * 256 + tid] = 1.f / (1.f + expf(-o));
    }
}

extern "C" void kernel_launch(void* const* d_in, const int* in_sizes, int n_in,
                              void* d_out, int out_size, void* d_ws, size_t ws_size,
                              hipStream_t stream) {
    const float* x   = (const float*)d_in[0];
    const float* wts = (const float*)d_in[1];
    const float* W1  = (const float*)d_in[2];
    const float* b1  = (const float*)d_in[3];
    const float* W2  = (const float*)d_in[4];
    const float* b2  = (const float*)d_in[5];
    float* out = (float*)d_out;
    unsigned short* Bp = (unsigned short*)d_ws;   // 65536 bf16 = 128 KB

    int B = in_sizes[0] >> 8;        // 65536 samples
    qnn_setup<<<64, 256, 0, stream>>>(wts, Bp);
    qnn_main<<<B / 256, 512, 0, stream>>>(x, Bp, W1, b1, W2, b2, out);
}